// Round 12
// baseline (118.761 us; speedup 1.0000x reference)
//
#include <hip/hip_runtime.h>
#include <hip/hip_bf16.h>

#define NROWS 4096
#define TWO_N 8192
#define DDIM 64
#define INV_T 20.0f
// exp(dot*INV_T) = 2^(dot*INV_T*log2e); fold sqrt of the scale into each operand
#define SCALE2 5.3716292f   // sqrt(20 * 1.4426950408889634)
#define NPANEL 64           // 8192 / 128

typedef short bf16x8 __attribute__((ext_vector_type(8)));
typedef float f32x4 __attribute__((ext_vector_type(4)));

__device__ __forceinline__ unsigned short f32_to_bf16_rne(float f) {
    unsigned int u = __float_as_uint(f);
    return (unsigned short)((u + 0x7fffu + ((u >> 16) & 1u)) >> 16);
}

__device__ __forceinline__ float fast_exp2(float x) {
    float r;
    asm("v_exp_f32 %0, %1" : "=v"(r) : "v"(x));
    return r;
}

// featsT fragment-major layout: element (row=16g+lr, col=kb*32+lk*8+e) at
//   featsT[g*1024 + kb*512 + (lk*16+lr)*8 + e]
// -> an MFMA fragment load is featsT + g*1024 + kb*512 + lane*8 (1KB coalesced).

// ---- kernel 1: convert f32 -> scaled bf16 fragment-major + posdot + zero out ----
__global__ void prep_kernel(const float* __restrict__ f1,
                            const float* __restrict__ f2,
                            unsigned short* __restrict__ featsT,
                            float* __restrict__ posdot,
                            float* __restrict__ out) {
    if (blockIdx.x == 0 && threadIdx.x == 0) out[0] = 0.f;
    int t = blockIdx.x * blockDim.x + threadIdx.x;
    int r = t >> 4;
    int q = t & 15;
    int j = r * DDIM + q * 4;
    float4 a = *reinterpret_cast<const float4*>(&f1[j]);
    float4 b = *reinterpret_cast<const float4*>(&f2[j]);
    float d = a.x * b.x + a.y * b.y + a.z * b.z + a.w * b.w;
    d += __shfl_xor(d, 1);
    d += __shfl_xor(d, 2);
    d += __shfl_xor(d, 4);
    d += __shfl_xor(d, 8);
    if (q == 0) posdot[r] = d * INV_T;
    ushort4 ua = make_ushort4(f32_to_bf16_rne(a.x * SCALE2), f32_to_bf16_rne(a.y * SCALE2),
                              f32_to_bf16_rne(a.z * SCALE2), f32_to_bf16_rne(a.w * SCALE2));
    ushort4 ub = make_ushort4(f32_to_bf16_rne(b.x * SCALE2), f32_to_bf16_rne(b.y * SCALE2),
                              f32_to_bf16_rne(b.z * SCALE2), f32_to_bf16_rne(b.w * SCALE2));
    int g1 = r >> 4;
    int lr = r & 15;
    int kb = q >> 3;
    int lk = (q & 7) >> 1;
    int e  = (q & 1) * 4;
    int off = g1 * 1024 + kb * 512 + (lk * 16 + lr) * 8 + e;
    *reinterpret_cast<ushort4*>(&featsT[off]) = ua;                 // f1: groups 0..255
    *reinterpret_cast<ushort4*>(&featsT[off + 256 * 1024]) = ub;    // f2: groups 256..511
}

// ---- kernel 2: upper-triangle 128x128 tiles; atomic-free symmetric partials ----
// Block (pr,pc), pc>=pr: 8 waves (4 wm x 2 wn), each a 32x64 sub-tile.
// Row sums  -> R[pc*8192 + pr*128 + r]  (read by final for k >= p)
// Col sums  -> C[pr*8192 + pc*128 + c]  (pr<pc only; read by final for k < p)
// Every slot final reads is written by exactly one block -> no init, no atomics.
__global__ __launch_bounds__(512) void ng_kernel(const unsigned short* __restrict__ featsT,
                                                 const int* __restrict__ label,
                                                 float* __restrict__ Rarr,
                                                 float* __restrict__ Carr) {
    const int pr = blockIdx.y;
    const int pc = blockIdx.x;
    if (pc < pr) return;

    __shared__ float rowP[2][128];   // [wn][row in tile]
    __shared__ float colP[4][128];   // [wm][col in tile]

    const int tid = threadIdx.x;
    const int wid = tid >> 6;
    const int lane = tid & 63;
    const int lr = lane & 15;
    const int lk = lane >> 4;
    const int wm = wid >> 1;         // 0..3
    const int wn = wid & 1;          // 0..1
    const int rowBase = pr * 128 + wm * 32;
    const int colBase = pc * 128 + wn * 64;
    const int gr0 = rowBase >> 4;
    const int gc0 = colBase >> 4;

    f32x4 acc[2][4];
    f32x4 zero = {0.f, 0.f, 0.f, 0.f};
    #pragma unroll
    for (int m = 0; m < 2; ++m)
        #pragma unroll
        for (int n = 0; n < 4; ++n) acc[m][n] = zero;

    #pragma unroll
    for (int kb = 0; kb < 2; ++kb) {
        bf16x8 afr[2], bfr[4];
        #pragma unroll
        for (int m = 0; m < 2; ++m)
            afr[m] = *reinterpret_cast<const bf16x8*>(
                &featsT[(gr0 + m) * 1024 + kb * 512 + lane * 8]);
        #pragma unroll
        for (int n = 0; n < 4; ++n)
            bfr[n] = *reinterpret_cast<const bf16x8*>(
                &featsT[(gc0 + n) * 1024 + kb * 512 + lane * 8]);
        #pragma unroll
        for (int m = 0; m < 2; ++m)
            #pragma unroll
            for (int n = 0; n < 4; ++n)
                acc[m][n] = __builtin_amdgcn_mfma_f32_16x16x32_bf16(afr[m], bfr[n], acc[m][n], 0, 0, 0);
    }

    int rl[2][4];
    #pragma unroll
    for (int m = 0; m < 2; ++m)
        #pragma unroll
        for (int r = 0; r < 4; ++r)
            rl[m][r] = label[(rowBase + m * 16 + lk * 4 + r) & (NROWS - 1)];
    int cl[4];
    #pragma unroll
    for (int n = 0; n < 4; ++n)
        cl[n] = label[(colBase + n * 16 + lr) & (NROWS - 1)];

    float rsum[2][4];
    float csum[4] = {0.f, 0.f, 0.f, 0.f};
    #pragma unroll
    for (int m = 0; m < 2; ++m)
        #pragma unroll
        for (int r = 0; r < 4; ++r) {
            int lab = rl[m][r];
            float s = 0.f;
            #pragma unroll
            for (int n = 0; n < 4; ++n) {
                float e = fast_exp2(acc[m][n][r]);   // = exp(dot/T)
                float me = (cl[n] != lab) ? e : 0.f;
                s += me;
                csum[n] += me;
            }
            rsum[m][r] = s;
        }

    // row sums: reduce across the 16 lr lanes -> rowP
    #pragma unroll
    for (int m = 0; m < 2; ++m)
        #pragma unroll
        for (int r = 0; r < 4; ++r) {
            float v = rsum[m][r];
            v += __shfl_xor(v, 1);
            v += __shfl_xor(v, 2);
            v += __shfl_xor(v, 4);
            v += __shfl_xor(v, 8);
            if (lr == 0) rowP[wn][wm * 32 + m * 16 + lk * 4 + r] = v;
        }
    // col sums: reduce across the 4 lk groups -> colP
    #pragma unroll
    for (int n = 0; n < 4; ++n) {
        float v = csum[n];
        v += __shfl_xor(v, 16);
        v += __shfl_xor(v, 32);
        if (lane < 16) colP[wm][wn * 64 + n * 16 + lr] = v;
    }
    __syncthreads();

    if (tid < 128) {
        Rarr[pc * TWO_N + pr * 128 + tid] = rowP[0][tid] + rowP[1][tid];
    } else if (tid < 256 && pr < pc) {
        int c = tid - 128;
        Carr[pr * TWO_N + pc * 128 + c] = colP[0][c] + colP[1][c] + colP[2][c] + colP[3][c];
    }
}

// ---- kernel 3: final loss; Ng[i] = sum_{k>=p} R[k][i] + sum_{k<p} C[k][i] ----
__global__ void final_kernel(const float* __restrict__ Rarr,
                             const float* __restrict__ Carr,
                             const float* __restrict__ posdot,
                             const int* __restrict__ label,
                             float* __restrict__ out) {
    __shared__ int cnt[16];
    __shared__ float red[4];
    int tid = threadIdx.x;
    if (tid < 16) cnt[tid] = 0;
    __syncthreads();
    for (int i = tid; i < NROWS; i += 256) atomicAdd(&cnt[label[i]], 1);
    __syncthreads();
    float s = 0.f;
    #pragma unroll
    for (int k = 0; k < 2; ++k) {
        int i = blockIdx.x * 512 + k * 256 + tid;
        int p = i >> 7;                      // wave-uniform (64 consecutive i per wave)
        float ng = 0.f;
        #pragma unroll 1
        for (int kk = 0; kk < NPANEL; ++kk) {
            const float* src = (kk >= p) ? Rarr : Carr;
            ng += src[kk * TWO_N + i];       // coalesced across lanes
        }
        int base = i & (NROWS - 1);
        float pd = posdot[base];
        float gs = 2.0f * (float)cnt[label[base]];
        s += (__logf(ng + __expf(pd)) - pd) / gs;
    }
    #pragma unroll
    for (int m = 32; m; m >>= 1) s += __shfl_xor(s, m);
    if ((tid & 63) == 0) red[tid >> 6] = s;
    __syncthreads();
    if (tid == 0) atomicAdd(out, red[0] + red[1] + red[2] + red[3]);
}

extern "C" void kernel_launch(void* const* d_in, const int* in_sizes, int n_in,
                              void* d_out, int out_size, void* d_ws, size_t ws_size,
                              hipStream_t stream) {
    const float* f1 = (const float*)d_in[0];
    const float* f2 = (const float*)d_in[1];
    const int* label = (const int*)d_in[2];
    float* out = (float*)d_out;

    char* ws = (char*)d_ws;
    unsigned short* featsT = (unsigned short*)ws;                    // 1 MB
    float* Rarr   = (float*)(ws + (1u << 20));                       // 2 MB
    float* Carr   = (float*)(ws + (3u << 20));                       // 2 MB
    float* posdot = (float*)(ws + (5u << 20));                       // 32 KB

    prep_kernel<<<dim3(NROWS * DDIM / 4 / 256), dim3(256), 0, stream>>>(f1, f2, featsT, posdot, out);
    ng_kernel<<<dim3(NPANEL, NPANEL), dim3(512), 0, stream>>>(featsT, label, Rarr, Carr);
    final_kernel<<<dim3(TWO_N / 512), dim3(256), 0, stream>>>(Rarr, Carr, posdot, label, out);
}

// Round 13
// 82.607 us; speedup vs baseline: 1.4377x; 1.4377x over previous
//
#include <hip/hip_runtime.h>
#include <hip/hip_bf16.h>

#define NROWS 4096
#define TWO_N 8192
#define DDIM 64
#define INV_T 20.0f
// exp(dot*INV_T) = 2^(dot*INV_T*log2e); fold sqrt of the scale into each operand
#define SCALE2 5.3716292f   // sqrt(20 * 1.4426950408889634)
#define NPANEL 64           // 8192 / 128

typedef short bf16x8 __attribute__((ext_vector_type(8)));
typedef float f32x4 __attribute__((ext_vector_type(4)));

__device__ __forceinline__ unsigned short f32_to_bf16_rne(float f) {
    unsigned int u = __float_as_uint(f);
    return (unsigned short)((u + 0x7fffu + ((u >> 16) & 1u)) >> 16);
}

__device__ __forceinline__ float fast_exp2(float x) {
    float r;
    asm("v_exp_f32 %0, %1" : "=v"(r) : "v"(x));
    return r;
}

// featsT fragment-major layout: element (row=16g+lr, col=kb*32+lk*8+e) at
//   featsT[g*1024 + kb*512 + (lk*16+lr)*8 + e]
// -> an MFMA fragment load is featsT + g*1024 + kb*512 + lane*8 (1KB coalesced).

// ---- kernel 1: convert f32 -> scaled bf16 fragment-major + posdot + zero out ----
__global__ void prep_kernel(const float* __restrict__ f1,
                            const float* __restrict__ f2,
                            unsigned short* __restrict__ featsT,
                            float* __restrict__ posdot,
                            float* __restrict__ out) {
    if (blockIdx.x == 0 && threadIdx.x == 0) out[0] = 0.f;
    int t = blockIdx.x * blockDim.x + threadIdx.x;
    int r = t >> 4;
    int q = t & 15;
    int j = r * DDIM + q * 4;
    float4 a = *reinterpret_cast<const float4*>(&f1[j]);
    float4 b = *reinterpret_cast<const float4*>(&f2[j]);
    float d = a.x * b.x + a.y * b.y + a.z * b.z + a.w * b.w;
    d += __shfl_xor(d, 1);
    d += __shfl_xor(d, 2);
    d += __shfl_xor(d, 4);
    d += __shfl_xor(d, 8);
    if (q == 0) posdot[r] = d * INV_T;
    ushort4 ua = make_ushort4(f32_to_bf16_rne(a.x * SCALE2), f32_to_bf16_rne(a.y * SCALE2),
                              f32_to_bf16_rne(a.z * SCALE2), f32_to_bf16_rne(a.w * SCALE2));
    ushort4 ub = make_ushort4(f32_to_bf16_rne(b.x * SCALE2), f32_to_bf16_rne(b.y * SCALE2),
                              f32_to_bf16_rne(b.z * SCALE2), f32_to_bf16_rne(b.w * SCALE2));
    int g1 = r >> 4;
    int lr = r & 15;
    int kb = q >> 3;
    int lk = (q & 7) >> 1;
    int e  = (q & 1) * 4;
    int off = g1 * 1024 + kb * 512 + (lk * 16 + lr) * 8 + e;
    *reinterpret_cast<ushort4*>(&featsT[off]) = ua;                 // f1: groups 0..255
    *reinterpret_cast<ushort4*>(&featsT[off + 256 * 1024]) = ub;    // f2: groups 256..511
}

// ---- kernel 2: upper-triangle 128x128 tiles; atomic-free symmetric partials ----
// Block (pr,pc), pc>=pr: 8 waves (4 wm x 2 wn), each a 32x64 sub-tile.
// Row sums -> NgP[pc][pr*128+r]; col sums -> NgP[pr][pc*128+c] (pr<pc only).
// For row i in panel p, slot NgP[k][i] is written by exactly one block:
// (p,k) rows for k>=p, (k,p) cols for k<p  ->  Ng[i] = sum_k NgP[k][i].
__global__ __launch_bounds__(512) void ng_kernel(const unsigned short* __restrict__ featsT,
                                                 const int* __restrict__ label,
                                                 float* __restrict__ NgP) {
    const int pr = blockIdx.y;
    const int pc = blockIdx.x;
    if (pc < pr) return;

    __shared__ float rowP[2][128];   // [wn][row in tile]
    __shared__ float colP[4][128];   // [wm][col in tile]

    const int tid = threadIdx.x;
    const int wid = tid >> 6;
    const int lane = tid & 63;
    const int lr = lane & 15;
    const int lk = lane >> 4;
    const int wm = wid >> 1;         // 0..3
    const int wn = wid & 1;          // 0..1
    const int rowBase = pr * 128 + wm * 32;
    const int colBase = pc * 128 + wn * 64;
    const int gr0 = rowBase >> 4;
    const int gc0 = colBase >> 4;

    f32x4 acc[2][4];
    f32x4 zero = {0.f, 0.f, 0.f, 0.f};
    #pragma unroll
    for (int m = 0; m < 2; ++m)
        #pragma unroll
        for (int n = 0; n < 4; ++n) acc[m][n] = zero;

    #pragma unroll
    for (int kb = 0; kb < 2; ++kb) {
        bf16x8 afr[2], bfr[4];
        #pragma unroll
        for (int m = 0; m < 2; ++m)
            afr[m] = *reinterpret_cast<const bf16x8*>(
                &featsT[(gr0 + m) * 1024 + kb * 512 + lane * 8]);
        #pragma unroll
        for (int n = 0; n < 4; ++n)
            bfr[n] = *reinterpret_cast<const bf16x8*>(
                &featsT[(gc0 + n) * 1024 + kb * 512 + lane * 8]);
        #pragma unroll
        for (int m = 0; m < 2; ++m)
            #pragma unroll
            for (int n = 0; n < 4; ++n)
                acc[m][n] = __builtin_amdgcn_mfma_f32_16x16x32_bf16(afr[m], bfr[n], acc[m][n], 0, 0, 0);
    }

    int rl[2][4];
    #pragma unroll
    for (int m = 0; m < 2; ++m)
        #pragma unroll
        for (int r = 0; r < 4; ++r)
            rl[m][r] = label[(rowBase + m * 16 + lk * 4 + r) & (NROWS - 1)];
    int cl[4];
    #pragma unroll
    for (int n = 0; n < 4; ++n)
        cl[n] = label[(colBase + n * 16 + lr) & (NROWS - 1)];

    float rsum[2][4];
    float csum[4] = {0.f, 0.f, 0.f, 0.f};
    #pragma unroll
    for (int m = 0; m < 2; ++m)
        #pragma unroll
        for (int r = 0; r < 4; ++r) {
            int lab = rl[m][r];
            float s = 0.f;
            #pragma unroll
            for (int n = 0; n < 4; ++n) {
                float e = fast_exp2(acc[m][n][r]);   // = exp(dot/T)
                float me = (cl[n] != lab) ? e : 0.f;
                s += me;
                csum[n] += me;
            }
            rsum[m][r] = s;
        }

    // row sums: reduce across the 16 lr lanes -> rowP
    #pragma unroll
    for (int m = 0; m < 2; ++m)
        #pragma unroll
        for (int r = 0; r < 4; ++r) {
            float v = rsum[m][r];
            v += __shfl_xor(v, 1);
            v += __shfl_xor(v, 2);
            v += __shfl_xor(v, 4);
            v += __shfl_xor(v, 8);
            if (lr == 0) rowP[wn][wm * 32 + m * 16 + lk * 4 + r] = v;
        }
    // col sums: reduce across the 4 lk groups -> colP
    #pragma unroll
    for (int n = 0; n < 4; ++n) {
        float v = csum[n];
        v += __shfl_xor(v, 16);
        v += __shfl_xor(v, 32);
        if (lane < 16) colP[wm][wn * 64 + n * 16 + lr] = v;
    }
    __syncthreads();

    if (tid < 128) {
        NgP[pc * TWO_N + pr * 128 + tid] = rowP[0][tid] + rowP[1][tid];
    } else if (tid < 256 && pr < pc) {
        int c = tid - 128;
        NgP[pr * TWO_N + pc * 128 + c] = colP[0][c] + colP[1][c] + colP[2][c] + colP[3][c];
    }
}

// ---- kernel 3: final loss; Ng[i] = sum_{k=0..63} NgP[k][i] (fully unrolled) ----
__global__ void final_kernel(const float* __restrict__ NgP,
                             const float* __restrict__ posdot,
                             const int* __restrict__ label,
                             float* __restrict__ out) {
    __shared__ int cnt[16];
    __shared__ float red[4];
    int tid = threadIdx.x;
    if (tid < 16) cnt[tid] = 0;
    __syncthreads();
    for (int i = tid; i < NROWS; i += 256) atomicAdd(&cnt[label[i]], 1);
    __syncthreads();

    int i = blockIdx.x * 256 + tid;
    float a0 = 0.f, a1 = 0.f, a2 = 0.f, a3 = 0.f;
    #pragma unroll
    for (int k = 0; k < NPANEL; k += 4) {
        a0 += NgP[(k + 0) * TWO_N + i];
        a1 += NgP[(k + 1) * TWO_N + i];
        a2 += NgP[(k + 2) * TWO_N + i];
        a3 += NgP[(k + 3) * TWO_N + i];
    }
    float ng = (a0 + a1) + (a2 + a3);
    int base = i & (NROWS - 1);
    float pd = posdot[base];
    float gs = 2.0f * (float)cnt[label[base]];
    float s = (__logf(ng + __expf(pd)) - pd) / gs;

    #pragma unroll
    for (int m = 32; m; m >>= 1) s += __shfl_xor(s, m);
    if ((tid & 63) == 0) red[tid >> 6] = s;
    __syncthreads();
    if (tid == 0) atomicAdd(out, red[0] + red[1] + red[2] + red[3]);
}

extern "C" void kernel_launch(void* const* d_in, const int* in_sizes, int n_in,
                              void* d_out, int out_size, void* d_ws, size_t ws_size,
                              hipStream_t stream) {
    const float* f1 = (const float*)d_in[0];
    const float* f2 = (const float*)d_in[1];
    const int* label = (const int*)d_in[2];
    float* out = (float*)d_out;

    char* ws = (char*)d_ws;
    unsigned short* featsT = (unsigned short*)ws;                    // 1 MB
    float* NgP    = (float*)(ws + (1u << 20));                       // 2 MB
    float* posdot = (float*)(ws + (3u << 20));                       // 32 KB

    prep_kernel<<<dim3(NROWS * DDIM / 4 / 256), dim3(256), 0, stream>>>(f1, f2, featsT, posdot, out);
    ng_kernel<<<dim3(NPANEL, NPANEL), dim3(512), 0, stream>>>(featsT, label, NgP);
    final_kernel<<<dim3(TWO_N / 256), dim3(256), 0, stream>>>(NgP, posdot, label, out);
}